// Round 8
// baseline (473.071 us; speedup 1.0000x reference)
//
#include <hip/hip_runtime.h>
#include <hip/hip_bf16.h>

#define N_NODES 100000
#define N_EDGES 1600000
#define N_TOT   (N_EDGES + N_NODES)   // edges + self loops
#define F_IN    256
#define F1      64     // H1*C1
#define H1      8
#define C1      8
#define F2      32
#define SLOPE   0.2f
#define CHUNK   2048
#define NCH     ((N_NODES + CHUNK - 1) / CHUNK)   // 49

#define NB_G    ((N_NODES + 255) / 256)           // 391 gemm blocks

#define SLICES  8                                  // one dst-slice per XCD
#define SL_W    ((N_NODES + SLICES - 1) / SLICES)  // 12500 nodes/slice
#define CH_E    16384                              // edges per chunk
#define NCHUNK  ((N_TOT + CH_E - 1) / CH_E)        // 104
#define NB_HS   (SLICES * NCHUNK)                  // 832 sliced-hist blocks

typedef unsigned int  uint;
typedef unsigned short ushort;
typedef __attribute__((ext_vector_type(8))) short bf16x8;
typedef __attribute__((ext_vector_type(4))) float f32x4;

__device__ inline ushort f2bf(float f) {               // RNE float->bf16
    uint u = __float_as_uint(f);
    uint r = u + 0x7fffu + ((u >> 16) & 1u);
    return (ushort)(r >> 16);
}
__device__ inline float bflo(uint u) { return __uint_as_float(u << 16); }
__device__ inline float bfhi(uint u) { return __uint_as_float(u & 0xffff0000u); }
__device__ inline uint pk2bf(float a, float b) {
    __hip_bfloat162 h = __float22bfloat162_rn(make_float2(a, b));
    union { __hip_bfloat162 h; uint u; } cv; cv.h = h;
    return cv.u;
}

// ---------------------------------------------------------------------------
// K1 fused: blocks [0,NB_G) = MFMA gemm (h1 = x@W1 + s1/d1 dots);
// blocks [NB_G, NB_G+NB_HS) = XCD-sliced hist+rank (slice = blockIdx%8
// pinned to one XCD -> L2-local cnt atomics).
// ---------------------------------------------------------------------------
__global__ __launch_bounds__(256) void k_gemm1_hist(
        const float* __restrict__ x, const float* __restrict__ W1,
        const float* __restrict__ as1, const float* __restrict__ ad1,
        const int* __restrict__ ei,
        ushort* __restrict__ h1b, float* __restrict__ s1, float* __restrict__ d1,
        int* __restrict__ cnt, int* __restrict__ rank) {
    __shared__ union {
        ushort B[F_IN * F1];        // 32 KB: W1 bf16, idx = ((k>>3)*64+n)*8 + (k&7)
        ushort S[4][64][66];        // 33.8 KB: per-wave h staging (pad 66)
    } sm;
    const int tid = threadIdx.x;

    if (blockIdx.x >= NB_G) {                      // ---- sliced hist part ----
        const int hb = blockIdx.x - NB_G;
        const int slice = blockIdx.x & 7;          // == XCD id (heuristic)
        const int chunk = hb >> 3;
        const int lo = slice * SL_W;
        const int base = chunk * CH_E;
        const int lim = (base + CH_E < N_TOT) ? base + CH_E : N_TOT;
        for (int i = base + tid; i < lim; i += 256) {
            const int di = (i < N_EDGES) ? ei[N_EDGES + i] : (i - N_EDGES);
            if ((uint)(di - lo) < (uint)SL_W)
                rank[i] = atomicAdd(cnt + di, 1);
        }
        return;
    }

    // ---- MFMA gemm part ----
    for (int i = 0; i < 64; ++i) {                 // stage + swizzle W1
        const int e = i * 256 + tid;               // e = k*64 + n
        const int k = e >> 6, n = e & 63;
        sm.B[((k >> 3) * 64 + n) * 8 + (k & 7)] = f2bf(W1[e]);
    }
    __syncthreads();

    const int wave = tid >> 6, lane = tid & 63;
    const int q = lane >> 4, ln = lane & 15;
    const int rowbase = blockIdx.x * 256 + wave * 64;

    f32x4 acc[4][4];
#pragma unroll
    for (int mt = 0; mt < 4; ++mt)
#pragma unroll
        for (int nt = 0; nt < 4; ++nt) acc[mt][nt] = (f32x4){0.f, 0.f, 0.f, 0.f};

    int rows[4];
#pragma unroll
    for (int mt = 0; mt < 4; ++mt) {
        const int r = rowbase + mt * 16 + ln;
        rows[mt] = r < N_NODES ? r : N_NODES - 1;
    }

    for (int t = 0; t < 8; ++t) {                  // K-loop: 8 x 32
        bf16x8 bfr[4];
#pragma unroll
        for (int nt = 0; nt < 4; ++nt)
            bfr[nt] = *(const bf16x8*)&sm.B[((t * 4 + q) * 64 + nt * 16 + ln) * 8];
#pragma unroll
        for (int mt = 0; mt < 4; ++mt) {
            const float4* ap = (const float4*)(x + (size_t)rows[mt] * F_IN + t * 32 + q * 8);
            const float4 a0 = ap[0], a1 = ap[1];
            uint4 au = make_uint4(pk2bf(a0.x, a0.y), pk2bf(a0.z, a0.w),
                                  pk2bf(a1.x, a1.y), pk2bf(a1.z, a1.w));
            bf16x8 af = *(bf16x8*)&au;
#pragma unroll
            for (int nt = 0; nt < 4; ++nt)
                acc[mt][nt] = __builtin_amdgcn_mfma_f32_16x16x32_bf16(
                                  af, bfr[nt], acc[mt][nt], 0, 0, 0);
        }
    }
    __syncthreads();

    // stage h (bf16): C/D layout col=lane&15, row=q*4+r
#pragma unroll
    for (int mt = 0; mt < 4; ++mt)
#pragma unroll
        for (int nt = 0; nt < 4; ++nt)
#pragma unroll
            for (int r = 0; r < 4; ++r)
                sm.S[wave][mt * 16 + q * 4 + r][nt * 16 + ln] = f2bf(acc[mt][nt][r]);
    __syncthreads();

    const int node = rowbase + lane;
    if (node >= N_NODES) return;
    const uint* srow = (const uint*)&sm.S[wave][lane][0];
    float sacc[H1], dacc[H1];
#pragma unroll
    for (int h = 0; h < H1; ++h) { sacc[h] = 0.f; dacc[h] = 0.f; }
    uint4* hout = (uint4*)(h1b + (size_t)node * F1);
#pragma unroll
    for (int p4 = 0; p4 < 8; ++p4) {               // p4 == head index
        const uint u0 = srow[p4 * 4 + 0], u1 = srow[p4 * 4 + 1];
        const uint u2 = srow[p4 * 4 + 2], u3 = srow[p4 * 4 + 3];
        hout[p4] = make_uint4(u0, u1, u2, u3);
        const float c[8] = {bflo(u0), bfhi(u0), bflo(u1), bfhi(u1),
                            bflo(u2), bfhi(u2), bflo(u3), bfhi(u3)};
#pragma unroll
        for (int j = 0; j < 8; ++j) {
            sacc[p4] += c[j] * as1[p4 * 8 + j];
            dacc[p4] += c[j] * ad1[p4 * 8 + j];
        }
    }
    float4* s4 = (float4*)(s1 + (size_t)node * H1);
    float4* d4 = (float4*)(d1 + (size_t)node * H1);
    s4[0] = make_float4(sacc[0], sacc[1], sacc[2], sacc[3]);
    s4[1] = make_float4(sacc[4], sacc[5], sacc[6], sacc[7]);
    d4[0] = make_float4(dacc[0], dacc[1], dacc[2], dacc[3]);
    d4[1] = make_float4(dacc[4], dacc[5], dacc[6], dacc[7]);
}

// ---------------------------------------------------------------------------
// Scan: per-chunk scan (a), then fused chunk-prefix + add (c2).
// ---------------------------------------------------------------------------
__global__ __launch_bounds__(256) void k_scan_a(
        const int* __restrict__ cnt, int* __restrict__ row_ptr,
        int* __restrict__ bsum) {
    __shared__ int sdata[256];
    const int tid = threadIdx.x;
    const int base = blockIdx.x * CHUNK + tid * 8;
    int v[8];
    int tot = 0;
#pragma unroll
    for (int j = 0; j < 8; ++j) {
        v[j] = (base + j < N_NODES) ? cnt[base + j] : 0;
        tot += v[j];
    }
    sdata[tid] = tot;
    __syncthreads();
    for (int off = 1; off < 256; off <<= 1) {
        int t = (tid >= off) ? sdata[tid - off] : 0;
        __syncthreads();
        sdata[tid] += t;
        __syncthreads();
    }
    int run = sdata[tid] - tot;
#pragma unroll
    for (int j = 0; j < 8; ++j) {
        if (base + j < N_NODES) row_ptr[base + j] = run;
        run += v[j];
    }
    if (tid == 255) bsum[blockIdx.x] = sdata[255];
}

__global__ __launch_bounds__(256) void k_scan_c2(
        int* __restrict__ row_ptr, const int* __restrict__ bsum) {
    __shared__ int pb[64];
    const int t = threadIdx.x;
    if (t < 64) {                       // wave 0: exclusive prefix of bsum
        int v = (t < NCH) ? bsum[t] : 0;
        const int orig = v;
        for (int off = 1; off < 64; off <<= 1) {
            int u = __shfl_up(v, off);
            if (t >= off) v += u;
        }
        pb[t] = v - orig;
    }
    __syncthreads();
    const int i = blockIdx.x * 256 + t;
    if (i < N_NODES) row_ptr[i] += pb[i / CHUNK];
    else if (i == N_NODES) row_ptr[N_NODES] = N_TOT;
}

// ---------------------------------------------------------------------------
// Sliced atomic-free scatter: slice = blockIdx%8 -> pinned to one XCD.
// ---------------------------------------------------------------------------
__global__ __launch_bounds__(256) void k_scatter(
        const int* __restrict__ ei, const int* __restrict__ row_ptr,
        const int* __restrict__ rank, int* __restrict__ srcs) {
    const int slice = blockIdx.x % SLICES;
    const int chunk = blockIdx.x / SLICES;
    const int lo = slice * SL_W;
    const int base = chunk * CH_E;
    const int lim = (base + CH_E < N_TOT) ? base + CH_E : N_TOT;
    for (int i = base + threadIdx.x; i < lim; i += 256) {
        const int di = (i < N_EDGES) ? ei[N_EDGES + i] : (i - N_EDGES);
        if ((uint)(di - lo) < (uint)SL_W) {
            const int si = (i < N_EDGES) ? ei[i] : di;
            srcs[row_ptr[di] + rank[i]] = si;
        }
    }
}

// ---------------------------------------------------------------------------
// K_agg1: 16 lanes/edge (4 groups), uint2 loads, unroll x2 -> 8 row-gathers
// in flight. Cheap epilogue (2 xor-reduces, elu, lanes<16 store x2b bf16).
// x2b row = 64 bf16 = 16 uint2 (NOT 8 -- that was the R6 bug).
// ---------------------------------------------------------------------------
__global__ __launch_bounds__(256) void k_agg1(
        const int* __restrict__ row_ptr, const int* __restrict__ srcs,
        const ushort* __restrict__ h1b, const float* __restrict__ s1,
        const float* __restrict__ d1, const float* __restrict__ b1,
        ushort* __restrict__ x2b) {
    const int wid = (blockIdx.x * 256 + threadIdx.x) >> 6;
    if (wid >= N_NODES) return;
    const int lane = threadIdx.x & 63;
    const int q = lane >> 4;          // edge group 0..3
    const int c = lane & 15;          // uint2 idx: channels 4c..4c+3
    const int hd = c >> 1;            // head
    const float dh = d1[(size_t)wid * H1 + hd];
    const int beg = row_ptr[wid], end = row_ptr[wid + 1];
    const uint2* hv = (const uint2*)h1b;      // 16 uint2 per node
    float a0 = 0.f, a1 = 0.f, a2 = 0.f, a3 = 0.f, z = 0.f;
    int i = beg + q;
    for (; i + 4 < end; i += 8) {             // edges i, i+4
        const int sA = srcs[i], sB = srcs[i + 4];
        float eA = s1[(size_t)sA * H1 + hd] + dh;
        float eB = s1[(size_t)sB * H1 + hd] + dh;
        eA = eA > 0.f ? eA : SLOPE * eA;
        eB = eB > 0.f ? eB : SLOPE * eB;
        const float xA = __expf(eA), xB = __expf(eB);
        const uint2 UA = hv[(size_t)sA * 16 + c];
        const uint2 UB = hv[(size_t)sB * 16 + c];
        z  += xA + xB;
        a0 += xA * bflo(UA.x) + xB * bflo(UB.x);
        a1 += xA * bfhi(UA.x) + xB * bfhi(UB.x);
        a2 += xA * bflo(UA.y) + xB * bflo(UB.y);
        a3 += xA * bfhi(UA.y) + xB * bfhi(UB.y);
    }
    for (; i < end; i += 4) {
        const int sA = srcs[i];
        float eA = s1[(size_t)sA * H1 + hd] + dh;
        eA = eA > 0.f ? eA : SLOPE * eA;
        const float xA = __expf(eA);
        const uint2 UA = hv[(size_t)sA * 16 + c];
        z  += xA;
        a0 += xA * bflo(UA.x);
        a1 += xA * bfhi(UA.x);
        a2 += xA * bflo(UA.y);
        a3 += xA * bfhi(UA.y);
    }
#pragma unroll
    for (int off = 16; off <= 32; off <<= 1) {
        a0 += __shfl_xor(a0, off); a1 += __shfl_xor(a1, off);
        a2 += __shfl_xor(a2, off); a3 += __shfl_xor(a3, off);
        z  += __shfl_xor(z, off);
    }
    if (lane < 16) {
        const float zi = 1.f / (z + 1e-16f);
        float v0 = a0 * zi + b1[4 * c + 0];
        float v1 = a1 * zi + b1[4 * c + 1];
        float v2 = a2 * zi + b1[4 * c + 2];
        float v3 = a3 * zi + b1[4 * c + 3];
        v0 = v0 > 0.f ? v0 : __expf(v0) - 1.f;     // elu
        v1 = v1 > 0.f ? v1 : __expf(v1) - 1.f;
        v2 = v2 > 0.f ? v2 : __expf(v2) - 1.f;
        v3 = v3 > 0.f ? v3 : __expf(v3) - 1.f;
        ((uint2*)x2b)[(size_t)wid * 16 + c] = make_uint2(pk2bf(v0, v1), pk2bf(v2, v3));
    }
}

// ---------------------------------------------------------------------------
// K_node1: h2 = x2 @ W2 (x2 bf16 in, h2 bf16 out, W2 in LDS), fused s2/d2.
// ---------------------------------------------------------------------------
__global__ __launch_bounds__(256) void k_node1(
        const ushort* __restrict__ x2b, const float* __restrict__ W2,
        const float* __restrict__ as2, const float* __restrict__ ad2,
        ushort* __restrict__ h2b, float* __restrict__ s2, float* __restrict__ d2) {
    __shared__ float sW[F1 * F2];           // 8 KB
    const int tid = threadIdx.x;
    const float4* W4 = (const float4*)W2;
    float4* sW4 = (float4*)sW;
#pragma unroll
    for (int i = 0; i < (F1 * F2 / 4) / 256; ++i)
        sW4[i * 256 + tid] = W4[i * 256 + tid];
    __syncthreads();

    const int n = blockIdx.x * 256 + tid;
    if (n >= N_NODES) return;

    float acc[F2];
#pragma unroll
    for (int c = 0; c < F2; ++c) acc[c] = 0.f;

    const uint4* xv4 = (const uint4*)(x2b + (size_t)n * F1);   // 8 loads
#pragma unroll
    for (int q = 0; q < 8; ++q) {
        uint4 u = xv4[q];
        float xs[8] = {bflo(u.x), bfhi(u.x), bflo(u.y), bfhi(u.y),
                       bflo(u.z), bfhi(u.z), bflo(u.w), bfhi(u.w)};
#pragma unroll
        for (int kk = 0; kk < 8; ++kk) {
            const float t = xs[kk];
            const float4* wr = (const float4*)(sW + (q * 8 + kk) * F2);
#pragma unroll
            for (int c4 = 0; c4 < F2 / 4; ++c4) {
                float4 w = wr[c4];
                acc[c4 * 4 + 0] += t * w.x;
                acc[c4 * 4 + 1] += t * w.y;
                acc[c4 * 4 + 2] += t * w.z;
                acc[c4 * 4 + 3] += t * w.w;
            }
        }
    }

    uint up[F2 / 2];
#pragma unroll
    for (int j = 0; j < F2 / 2; ++j)
        up[j] = (uint)f2bf(acc[2 * j]) | ((uint)f2bf(acc[2 * j + 1]) << 16);
    uint4* o4 = (uint4*)(h2b + (size_t)n * F2);
#pragma unroll
    for (int q = 0; q < F2 / 8; ++q)
        o4[q] = make_uint4(up[q * 4 + 0], up[q * 4 + 1], up[q * 4 + 2], up[q * 4 + 3]);

    float s = 0.f, d = 0.f;
#pragma unroll
    for (int c = 0; c < F2; ++c) { s += acc[c] * as2[c]; d += acc[c] * ad2[c]; }
    s2[n] = s;
    d2[n] = d;
}

// ---------------------------------------------------------------------------
// K_agg2: 8 lanes/edge (8 groups), uint2 loads, unroll x2 -> 16 gathers in
// flight. Fused log_softmax. Writes d_out directly.
// ---------------------------------------------------------------------------
__global__ __launch_bounds__(256) void k_agg2(
        const int* __restrict__ row_ptr, const int* __restrict__ srcs,
        const ushort* __restrict__ h2b, const float* __restrict__ s2,
        const float* __restrict__ d2, const float* __restrict__ b2,
        float* __restrict__ out) {
    const int wid = (blockIdx.x * 256 + threadIdx.x) >> 6;
    if (wid >= N_NODES) return;
    const int lane = threadIdx.x & 63;
    const int q = lane >> 3;          // edge group 0..7
    const int c = lane & 7;           // uint2 idx: channels 4c..4c+3
    const float dn = d2[wid];
    const int beg = row_ptr[wid], end = row_ptr[wid + 1];
    const uint2* hv = (const uint2*)h2b;      // 8 uint2 per node
    float a0 = 0.f, a1 = 0.f, a2 = 0.f, a3 = 0.f, z = 0.f;
    int i = beg + q;
    for (; i + 8 < end; i += 16) {            // edges i, i+8
        const int sA = srcs[i], sB = srcs[i + 8];
        float eA = s2[sA] + dn;
        float eB = s2[sB] + dn;
        eA = eA > 0.f ? eA : SLOPE * eA;
        eB = eB > 0.f ? eB : SLOPE * eB;
        const float xA = __expf(eA), xB = __expf(eB);
        const uint2 UA = hv[(size_t)sA * 8 + c];
        const uint2 UB = hv[(size_t)sB * 8 + c];
        z  += xA + xB;
        a0 += xA * bflo(UA.x) + xB * bflo(UB.x);
        a1 += xA * bfhi(UA.x) + xB * bfhi(UB.x);
        a2 += xA * bflo(UA.y) + xB * bflo(UB.y);
        a3 += xA * bfhi(UA.y) + xB * bfhi(UB.y);
    }
    for (; i < end; i += 8) {
        const int sA = srcs[i];
        float eA = s2[sA] + dn;
        eA = eA > 0.f ? eA : SLOPE * eA;
        const float xA = __expf(eA);
        const uint2 UA = hv[(size_t)sA * 8 + c];
        z  += xA;
        a0 += xA * bflo(UA.x);
        a1 += xA * bfhi(UA.x);
        a2 += xA * bflo(UA.y);
        a3 += xA * bfhi(UA.y);
    }
#pragma unroll
    for (int off = 8; off <= 32; off <<= 1) {
        a0 += __shfl_xor(a0, off); a1 += __shfl_xor(a1, off);
        a2 += __shfl_xor(a2, off); a3 += __shfl_xor(a3, off);
        z  += __shfl_xor(z, off);
    }
    const float zi = 1.f / (z + 1e-16f);
    const float v0 = a0 * zi + b2[4 * c + 0];
    const float v1 = a1 * zi + b2[4 * c + 1];
    const float v2 = a2 * zi + b2[4 * c + 2];
    const float v3 = a3 * zi + b2[4 * c + 3];
    float m = fmaxf(fmaxf(v0, v1), fmaxf(v2, v3));
#pragma unroll
    for (int off = 1; off <= 4; off <<= 1) m = fmaxf(m, __shfl_xor(m, off));
    float ssum = __expf(v0 - m) + __expf(v1 - m) + __expf(v2 - m) + __expf(v3 - m);
#pragma unroll
    for (int off = 1; off <= 4; off <<= 1) ssum += __shfl_xor(ssum, off);
    const float lse = m + __logf(ssum);
    if (lane < 8)
        ((float4*)out)[(size_t)wid * 8 + c] =
            make_float4(v0 - lse, v1 - lse, v2 - lse, v3 - lse);
}

extern "C" void kernel_launch(void* const* d_in, const int* in_sizes, int n_in,
                              void* d_out, int out_size, void* d_ws, size_t ws_size,
                              hipStream_t stream) {
    const float* x   = (const float*)d_in[0];
    const int*   ei  = (const int*)d_in[1];
    const float* W1  = (const float*)d_in[2];
    const float* as1 = (const float*)d_in[3];
    const float* ad1 = (const float*)d_in[4];
    const float* b1  = (const float*)d_in[5];
    const float* W2  = (const float*)d_in[6];
    const float* as2 = (const float*)d_in[7];
    const float* ad2 = (const float*)d_in[8];
    const float* b2  = (const float*)d_in[9];
    float* out = (float*)d_out;

    // Workspace layout
    ushort* h1b = (ushort*)d_ws;                   // N*64 bf16
    ushort* x2b = h1b + (size_t)N_NODES * F1;      // N*64 bf16
    ushort* h2b = x2b + (size_t)N_NODES * F1;      // N*32 bf16
    float*  s1  = (float*)(h2b + (size_t)N_NODES * F2);  // N*8
    float*  d1  = s1 + (size_t)N_NODES * H1;       // N*8
    float*  s2  = d1 + (size_t)N_NODES * H1;       // N
    float*  d2  = s2 + N_NODES;                    // N
    int* cnt     = (int*)(d2 + N_NODES);           // N
    int* rank    = cnt + N_NODES;                  // N_TOT
    int* row_ptr = rank + N_TOT;                   // N+1
    int* bsum    = row_ptr + N_NODES + 1;          // 64
    int* srcs    = bsum + 64;                      // N_TOT

    hipMemsetAsync(cnt, 0, (size_t)N_NODES * sizeof(int), stream);

    const int nb_n = (N_NODES + 255) / 256;
    const int nb_w = (N_NODES * 64 + 255) / 256;   // one wave per node

    k_gemm1_hist<<<NB_G + NB_HS, 256, 0, stream>>>(x, W1, as1, ad1, ei,
                                                   h1b, s1, d1, cnt, rank);
    k_scan_a<<<NCH, 256, 0, stream>>>(cnt, row_ptr, bsum);
    k_scan_c2<<<(N_NODES + 256) / 256, 256, 0, stream>>>(row_ptr, bsum);
    k_scatter<<<SLICES * NCHUNK, 256, 0, stream>>>(ei, row_ptr, rank, srcs);
    k_agg1<<<nb_w, 256, 0, stream>>>(row_ptr, srcs, h1b, s1, d1, b1, x2b);
    k_node1<<<nb_n, 256, 0, stream>>>(x2b, W2, as2, ad2, h2b, s2, d2);
    k_agg2<<<nb_w, 256, 0, stream>>>(row_ptr, srcs, h2b, s2, d2, b2, out);
}

// Round 9
// 401.309 us; speedup vs baseline: 1.1788x; 1.1788x over previous
//
#include <hip/hip_runtime.h>
#include <hip/hip_bf16.h>

#define N_NODES 100000
#define N_EDGES 1600000
#define N_TOT   (N_EDGES + N_NODES)   // edges + self loops
#define F_IN    256
#define F1      64     // H1*C1
#define H1      8
#define C1      8
#define F2      32
#define SLOPE   0.2f
#define CHUNK   2048
#define NCH     ((N_NODES + CHUNK - 1) / CHUNK)   // 49

#define NB_G    ((N_NODES + 255) / 256)           // 391 gemm blocks
#define NB_H    ((N_EDGES + 255) / 256)           // 6250 hist blocks (real edges only)

#define SLICES  8                                  // one dst-slice per XCD
#define SL_W    ((N_NODES + SLICES - 1) / SLICES)  // 12500 nodes/slice
#define CH_E    16384                              // edges per scatter chunk
#define NCHUNK  ((N_EDGES + CH_E - 1) / CH_E)      // 98

typedef unsigned int  uint;
typedef unsigned short ushort;
typedef __attribute__((ext_vector_type(8))) short bf16x8;
typedef __attribute__((ext_vector_type(4))) float f32x4;

__device__ inline ushort f2bf(float f) {               // RNE float->bf16
    uint u = __float_as_uint(f);
    uint r = u + 0x7fffu + ((u >> 16) & 1u);
    return (ushort)(r >> 16);
}
__device__ inline float bflo(uint u) { return __uint_as_float(u << 16); }
__device__ inline float bfhi(uint u) { return __uint_as_float(u & 0xffff0000u); }
__device__ inline uint pk2bf(float a, float b) {
    __hip_bfloat162 h = __float22bfloat162_rn(make_float2(a, b));
    union { __hip_bfloat162 h; uint u; } cv; cv.h = h;
    return cv.u;
}

// ---------------------------------------------------------------------------
// K1 fused: blocks [0,NB_G) = MFMA gemm (h1 = x@W1 + s1/d1 dots);
// blocks [NB_G, NB_G+NB_H) = hist+rank over REAL edges only (self-loops get
// reserved slot 0 per segment -- no atomic needed for them). Device-scope
// atomic rank is ~20 Gops/s structural (R7 showed XCD-slicing doesn't help);
// the gemm hides under the atomic window.
// ---------------------------------------------------------------------------
__global__ __launch_bounds__(256) void k_gemm1_hist(
        const float* __restrict__ x, const float* __restrict__ W1,
        const float* __restrict__ as1, const float* __restrict__ ad1,
        const int* __restrict__ ei,
        ushort* __restrict__ h1b, float* __restrict__ s1, float* __restrict__ d1,
        int* __restrict__ cnt, int* __restrict__ rank) {
    __shared__ union {
        ushort B[F_IN * F1];        // 32 KB: W1 bf16, idx = ((k>>3)*64+n)*8 + (k&7)
        ushort S[4][64][66];        // 33.8 KB: per-wave h staging (pad 66)
    } sm;
    const int tid = threadIdx.x;

    if (blockIdx.x >= NB_G) {                      // ---- hist + rank part ----
        const int e = (blockIdx.x - NB_G) * 256 + tid;
        if (e < N_EDGES)
            rank[e] = atomicAdd(cnt + ei[N_EDGES + e], 1);
        return;
    }

    // ---- MFMA gemm part ----
    for (int i = 0; i < 64; ++i) {                 // stage + swizzle W1
        const int e = i * 256 + tid;               // e = k*64 + n
        const int k = e >> 6, n = e & 63;
        sm.B[((k >> 3) * 64 + n) * 8 + (k & 7)] = f2bf(W1[e]);
    }
    __syncthreads();

    const int wave = tid >> 6, lane = tid & 63;
    const int q = lane >> 4, ln = lane & 15;
    const int rowbase = blockIdx.x * 256 + wave * 64;

    f32x4 acc[4][4];
#pragma unroll
    for (int mt = 0; mt < 4; ++mt)
#pragma unroll
        for (int nt = 0; nt < 4; ++nt) acc[mt][nt] = (f32x4){0.f, 0.f, 0.f, 0.f};

    int rows[4];
#pragma unroll
    for (int mt = 0; mt < 4; ++mt) {
        const int r = rowbase + mt * 16 + ln;
        rows[mt] = r < N_NODES ? r : N_NODES - 1;
    }

    for (int t = 0; t < 8; ++t) {                  // K-loop: 8 x 32
        bf16x8 bfr[4];
#pragma unroll
        for (int nt = 0; nt < 4; ++nt)
            bfr[nt] = *(const bf16x8*)&sm.B[((t * 4 + q) * 64 + nt * 16 + ln) * 8];
#pragma unroll
        for (int mt = 0; mt < 4; ++mt) {
            const float4* ap = (const float4*)(x + (size_t)rows[mt] * F_IN + t * 32 + q * 8);
            const float4 a0 = ap[0], a1 = ap[1];
            uint4 au = make_uint4(pk2bf(a0.x, a0.y), pk2bf(a0.z, a0.w),
                                  pk2bf(a1.x, a1.y), pk2bf(a1.z, a1.w));
            bf16x8 af = *(bf16x8*)&au;
#pragma unroll
            for (int nt = 0; nt < 4; ++nt)
                acc[mt][nt] = __builtin_amdgcn_mfma_f32_16x16x32_bf16(
                                  af, bfr[nt], acc[mt][nt], 0, 0, 0);
        }
    }
    __syncthreads();

    // stage h (bf16): C/D layout col=lane&15, row=q*4+r
#pragma unroll
    for (int mt = 0; mt < 4; ++mt)
#pragma unroll
        for (int nt = 0; nt < 4; ++nt)
#pragma unroll
            for (int r = 0; r < 4; ++r)
                sm.S[wave][mt * 16 + q * 4 + r][nt * 16 + ln] = f2bf(acc[mt][nt][r]);
    __syncthreads();

    const int node = rowbase + lane;
    if (node >= N_NODES) return;
    const uint* srow = (const uint*)&sm.S[wave][lane][0];
    float sacc[H1], dacc[H1];
#pragma unroll
    for (int h = 0; h < H1; ++h) { sacc[h] = 0.f; dacc[h] = 0.f; }
    uint4* hout = (uint4*)(h1b + (size_t)node * F1);
#pragma unroll
    for (int p4 = 0; p4 < 8; ++p4) {               // p4 == head index
        const uint u0 = srow[p4 * 4 + 0], u1 = srow[p4 * 4 + 1];
        const uint u2 = srow[p4 * 4 + 2], u3 = srow[p4 * 4 + 3];
        hout[p4] = make_uint4(u0, u1, u2, u3);
        const float c[8] = {bflo(u0), bfhi(u0), bflo(u1), bfhi(u1),
                            bflo(u2), bfhi(u2), bflo(u3), bfhi(u3)};
#pragma unroll
        for (int j = 0; j < 8; ++j) {
            sacc[p4] += c[j] * as1[p4 * 8 + j];
            dacc[p4] += c[j] * ad1[p4 * 8 + j];
        }
    }
    float4* s4 = (float4*)(s1 + (size_t)node * H1);
    float4* d4 = (float4*)(d1 + (size_t)node * H1);
    s4[0] = make_float4(sacc[0], sacc[1], sacc[2], sacc[3]);
    s4[1] = make_float4(sacc[4], sacc[5], sacc[6], sacc[7]);
    d4[0] = make_float4(dacc[0], dacc[1], dacc[2], dacc[3]);
    d4[1] = make_float4(dacc[4], dacc[5], dacc[6], dacc[7]);
}

// ---------------------------------------------------------------------------
// Scan: per-chunk scan (a) with +1 per node (reserved self-loop slot), then
// fused chunk-prefix + add + self-loop emit (c2).
// ---------------------------------------------------------------------------
__global__ __launch_bounds__(256) void k_scan_a(
        const int* __restrict__ cnt, int* __restrict__ row_ptr,
        int* __restrict__ bsum) {
    __shared__ int sdata[256];
    const int tid = threadIdx.x;
    const int base = blockIdx.x * CHUNK + tid * 8;
    int v[8];
    int tot = 0;
#pragma unroll
    for (int j = 0; j < 8; ++j) {
        v[j] = (base + j < N_NODES) ? cnt[base + j] + 1 : 0;   // +1 = self loop
        tot += v[j];
    }
    sdata[tid] = tot;
    __syncthreads();
    for (int off = 1; off < 256; off <<= 1) {
        int t = (tid >= off) ? sdata[tid - off] : 0;
        __syncthreads();
        sdata[tid] += t;
        __syncthreads();
    }
    int run = sdata[tid] - tot;
#pragma unroll
    for (int j = 0; j < 8; ++j) {
        if (base + j < N_NODES) row_ptr[base + j] = run;
        run += v[j];
    }
    if (tid == 255) bsum[blockIdx.x] = sdata[255];
}

__global__ __launch_bounds__(256) void k_scan_c2(
        int* __restrict__ row_ptr, const int* __restrict__ bsum,
        int* __restrict__ srcs) {
    __shared__ int pb[64];
    const int t = threadIdx.x;
    if (t < 64) {                       // wave 0: exclusive prefix of bsum
        int v = (t < NCH) ? bsum[t] : 0;
        const int orig = v;
        for (int off = 1; off < 64; off <<= 1) {
            int u = __shfl_up(v, off);
            if (t >= off) v += u;
        }
        pb[t] = v - orig;
    }
    __syncthreads();
    const int i = blockIdx.x * 256 + t;
    if (i < N_NODES) {
        const int rp = row_ptr[i] + pb[i / CHUNK];
        row_ptr[i] = rp;
        srcs[rp] = i;                   // self loop occupies segment slot 0
    } else if (i == N_NODES) row_ptr[N_NODES] = N_TOT;
}

// ---------------------------------------------------------------------------
// Sliced atomic-free scatter over real edges: slice = blockIdx%8 -> one XCD.
// Real edges land at row_ptr[d] + 1 + rank (slot 0 = self loop).
// ---------------------------------------------------------------------------
__global__ __launch_bounds__(256) void k_scatter(
        const int* __restrict__ ei, const int* __restrict__ row_ptr,
        const int* __restrict__ rank, int* __restrict__ srcs) {
    const int slice = blockIdx.x % SLICES;
    const int chunk = blockIdx.x / SLICES;
    const int lo = slice * SL_W;
    const int base = chunk * CH_E;
    const int lim = (base + CH_E < N_EDGES) ? base + CH_E : N_EDGES;
    for (int i = base + threadIdx.x; i < lim; i += 256) {
        const int di = ei[N_EDGES + i];
        if ((uint)(di - lo) < (uint)SL_W)
            srcs[row_ptr[di] + 1 + rank[i]] = ei[i];
    }
}

// ---------------------------------------------------------------------------
// K_agg1: 16 lanes/edge (4 groups), uint2 loads, unroll x2 -> 8 row-gathers
// in flight. Cheap epilogue (2 xor-reduces, elu, lanes<16 store x2b bf16).
// x2b row = 64 bf16 = 16 uint2.
// ---------------------------------------------------------------------------
__global__ __launch_bounds__(256) void k_agg1(
        const int* __restrict__ row_ptr, const int* __restrict__ srcs,
        const ushort* __restrict__ h1b, const float* __restrict__ s1,
        const float* __restrict__ d1, const float* __restrict__ b1,
        ushort* __restrict__ x2b) {
    const int wid = (blockIdx.x * 256 + threadIdx.x) >> 6;
    if (wid >= N_NODES) return;
    const int lane = threadIdx.x & 63;
    const int q = lane >> 4;          // edge group 0..3
    const int c = lane & 15;          // uint2 idx: channels 4c..4c+3
    const int hd = c >> 1;            // head
    const float dh = d1[(size_t)wid * H1 + hd];
    const int beg = row_ptr[wid], end = row_ptr[wid + 1];
    const uint2* hv = (const uint2*)h1b;      // 16 uint2 per node
    float a0 = 0.f, a1 = 0.f, a2 = 0.f, a3 = 0.f, z = 0.f;
    int i = beg + q;
    for (; i + 4 < end; i += 8) {             // edges i, i+4
        const int sA = srcs[i], sB = srcs[i + 4];
        float eA = s1[(size_t)sA * H1 + hd] + dh;
        float eB = s1[(size_t)sB * H1 + hd] + dh;
        eA = eA > 0.f ? eA : SLOPE * eA;
        eB = eB > 0.f ? eB : SLOPE * eB;
        const float xA = __expf(eA), xB = __expf(eB);
        const uint2 UA = hv[(size_t)sA * 16 + c];
        const uint2 UB = hv[(size_t)sB * 16 + c];
        z  += xA + xB;
        a0 += xA * bflo(UA.x) + xB * bflo(UB.x);
        a1 += xA * bfhi(UA.x) + xB * bfhi(UB.x);
        a2 += xA * bflo(UA.y) + xB * bflo(UB.y);
        a3 += xA * bfhi(UA.y) + xB * bfhi(UB.y);
    }
    for (; i < end; i += 4) {
        const int sA = srcs[i];
        float eA = s1[(size_t)sA * H1 + hd] + dh;
        eA = eA > 0.f ? eA : SLOPE * eA;
        const float xA = __expf(eA);
        const uint2 UA = hv[(size_t)sA * 16 + c];
        z  += xA;
        a0 += xA * bflo(UA.x);
        a1 += xA * bfhi(UA.x);
        a2 += xA * bflo(UA.y);
        a3 += xA * bfhi(UA.y);
    }
#pragma unroll
    for (int off = 16; off <= 32; off <<= 1) {
        a0 += __shfl_xor(a0, off); a1 += __shfl_xor(a1, off);
        a2 += __shfl_xor(a2, off); a3 += __shfl_xor(a3, off);
        z  += __shfl_xor(z, off);
    }
    if (lane < 16) {
        const float zi = 1.f / (z + 1e-16f);
        float v0 = a0 * zi + b1[4 * c + 0];
        float v1 = a1 * zi + b1[4 * c + 1];
        float v2 = a2 * zi + b1[4 * c + 2];
        float v3 = a3 * zi + b1[4 * c + 3];
        v0 = v0 > 0.f ? v0 : __expf(v0) - 1.f;     // elu
        v1 = v1 > 0.f ? v1 : __expf(v1) - 1.f;
        v2 = v2 > 0.f ? v2 : __expf(v2) - 1.f;
        v3 = v3 > 0.f ? v3 : __expf(v3) - 1.f;
        ((uint2*)x2b)[(size_t)wid * 16 + c] = make_uint2(pk2bf(v0, v1), pk2bf(v2, v3));
    }
}

// ---------------------------------------------------------------------------
// K_node1: h2 = x2 @ W2 (x2 bf16 in, h2 bf16 out, W2 in LDS), fused s2/d2.
// ---------------------------------------------------------------------------
__global__ __launch_bounds__(256) void k_node1(
        const ushort* __restrict__ x2b, const float* __restrict__ W2,
        const float* __restrict__ as2, const float* __restrict__ ad2,
        ushort* __restrict__ h2b, float* __restrict__ s2, float* __restrict__ d2) {
    __shared__ float sW[F1 * F2];           // 8 KB
    const int tid = threadIdx.x;
    const float4* W4 = (const float4*)W2;
    float4* sW4 = (float4*)sW;
#pragma unroll
    for (int i = 0; i < (F1 * F2 / 4) / 256; ++i)
        sW4[i * 256 + tid] = W4[i * 256 + tid];
    __syncthreads();

    const int n = blockIdx.x * 256 + tid;
    if (n >= N_NODES) return;

    float acc[F2];
#pragma unroll
    for (int c = 0; c < F2; ++c) acc[c] = 0.f;

    const uint4* xv4 = (const uint4*)(x2b + (size_t)n * F1);   // 8 loads
#pragma unroll
    for (int q = 0; q < 8; ++q) {
        uint4 u = xv4[q];
        float xs[8] = {bflo(u.x), bfhi(u.x), bflo(u.y), bfhi(u.y),
                       bflo(u.z), bfhi(u.z), bflo(u.w), bfhi(u.w)};
#pragma unroll
        for (int kk = 0; kk < 8; ++kk) {
            const float t = xs[kk];
            const float4* wr = (const float4*)(sW + (q * 8 + kk) * F2);
#pragma unroll
            for (int c4 = 0; c4 < F2 / 4; ++c4) {
                float4 w = wr[c4];
                acc[c4 * 4 + 0] += t * w.x;
                acc[c4 * 4 + 1] += t * w.y;
                acc[c4 * 4 + 2] += t * w.z;
                acc[c4 * 4 + 3] += t * w.w;
            }
        }
    }

    uint up[F2 / 2];
#pragma unroll
    for (int j = 0; j < F2 / 2; ++j)
        up[j] = (uint)f2bf(acc[2 * j]) | ((uint)f2bf(acc[2 * j + 1]) << 16);
    uint4* o4 = (uint4*)(h2b + (size_t)n * F2);
#pragma unroll
    for (int q = 0; q < F2 / 8; ++q)
        o4[q] = make_uint4(up[q * 4 + 0], up[q * 4 + 1], up[q * 4 + 2], up[q * 4 + 3]);

    float s = 0.f, d = 0.f;
#pragma unroll
    for (int c = 0; c < F2; ++c) { s += acc[c] * as2[c]; d += acc[c] * ad2[c]; }
    s2[n] = s;
    d2[n] = d;
}

// ---------------------------------------------------------------------------
// K_agg2: 8 lanes/edge (8 groups), uint2 loads, unroll x2 -> 16 gathers in
// flight. Fused log_softmax. Writes d_out directly.
// ---------------------------------------------------------------------------
__global__ __launch_bounds__(256) void k_agg2(
        const int* __restrict__ row_ptr, const int* __restrict__ srcs,
        const ushort* __restrict__ h2b, const float* __restrict__ s2,
        const float* __restrict__ d2, const float* __restrict__ b2,
        float* __restrict__ out) {
    const int wid = (blockIdx.x * 256 + threadIdx.x) >> 6;
    if (wid >= N_NODES) return;
    const int lane = threadIdx.x & 63;
    const int q = lane >> 3;          // edge group 0..7
    const int c = lane & 7;           // uint2 idx: channels 4c..4c+3
    const float dn = d2[wid];
    const int beg = row_ptr[wid], end = row_ptr[wid + 1];
    const uint2* hv = (const uint2*)h2b;      // 8 uint2 per node
    float a0 = 0.f, a1 = 0.f, a2 = 0.f, a3 = 0.f, z = 0.f;
    int i = beg + q;
    for (; i + 8 < end; i += 16) {            // edges i, i+8
        const int sA = srcs[i], sB = srcs[i + 8];
        float eA = s2[sA] + dn;
        float eB = s2[sB] + dn;
        eA = eA > 0.f ? eA : SLOPE * eA;
        eB = eB > 0.f ? eB : SLOPE * eB;
        const float xA = __expf(eA), xB = __expf(eB);
        const uint2 UA = hv[(size_t)sA * 8 + c];
        const uint2 UB = hv[(size_t)sB * 8 + c];
        z  += xA + xB;
        a0 += xA * bflo(UA.x) + xB * bflo(UB.x);
        a1 += xA * bfhi(UA.x) + xB * bfhi(UB.x);
        a2 += xA * bflo(UA.y) + xB * bflo(UB.y);
        a3 += xA * bfhi(UA.y) + xB * bfhi(UB.y);
    }
    for (; i < end; i += 8) {
        const int sA = srcs[i];
        float eA = s2[sA] + dn;
        eA = eA > 0.f ? eA : SLOPE * eA;
        const float xA = __expf(eA);
        const uint2 UA = hv[(size_t)sA * 8 + c];
        z  += xA;
        a0 += xA * bflo(UA.x);
        a1 += xA * bfhi(UA.x);
        a2 += xA * bflo(UA.y);
        a3 += xA * bfhi(UA.y);
    }
#pragma unroll
    for (int off = 8; off <= 32; off <<= 1) {
        a0 += __shfl_xor(a0, off); a1 += __shfl_xor(a1, off);
        a2 += __shfl_xor(a2, off); a3 += __shfl_xor(a3, off);
        z  += __shfl_xor(z, off);
    }
    const float zi = 1.f / (z + 1e-16f);
    const float v0 = a0 * zi + b2[4 * c + 0];
    const float v1 = a1 * zi + b2[4 * c + 1];
    const float v2 = a2 * zi + b2[4 * c + 2];
    const float v3 = a3 * zi + b2[4 * c + 3];
    float m = fmaxf(fmaxf(v0, v1), fmaxf(v2, v3));
#pragma unroll
    for (int off = 1; off <= 4; off <<= 1) m = fmaxf(m, __shfl_xor(m, off));
    float ssum = __expf(v0 - m) + __expf(v1 - m) + __expf(v2 - m) + __expf(v3 - m);
#pragma unroll
    for (int off = 1; off <= 4; off <<= 1) ssum += __shfl_xor(ssum, off);
    const float lse = m + __logf(ssum);
    if (lane < 8)
        ((float4*)out)[(size_t)wid * 8 + c] =
            make_float4(v0 - lse, v1 - lse, v2 - lse, v3 - lse);
}

extern "C" void kernel_launch(void* const* d_in, const int* in_sizes, int n_in,
                              void* d_out, int out_size, void* d_ws, size_t ws_size,
                              hipStream_t stream) {
    const float* x   = (const float*)d_in[0];
    const int*   ei  = (const int*)d_in[1];
    const float* W1  = (const float*)d_in[2];
    const float* as1 = (const float*)d_in[3];
    const float* ad1 = (const float*)d_in[4];
    const float* b1  = (const float*)d_in[5];
    const float* W2  = (const float*)d_in[6];
    const float* as2 = (const float*)d_in[7];
    const float* ad2 = (const float*)d_in[8];
    const float* b2  = (const float*)d_in[9];
    float* out = (float*)d_out;

    // Workspace layout
    ushort* h1b = (ushort*)d_ws;                   // N*64 bf16
    ushort* x2b = h1b + (size_t)N_NODES * F1;      // N*64 bf16
    ushort* h2b = x2b + (size_t)N_NODES * F1;      // N*32 bf16
    float*  s1  = (float*)(h2b + (size_t)N_NODES * F2);  // N*8
    float*  d1  = s1 + (size_t)N_NODES * H1;       // N*8
    float*  s2  = d1 + (size_t)N_NODES * H1;       // N
    float*  d2  = s2 + N_NODES;                    // N
    int* cnt     = (int*)(d2 + N_NODES);           // N
    int* rank    = cnt + N_NODES;                  // N_EDGES
    int* row_ptr = rank + N_EDGES;                 // N+1
    int* bsum    = row_ptr + N_NODES + 1;          // 64
    int* srcs    = bsum + 64;                      // N_TOT

    hipMemsetAsync(cnt, 0, (size_t)N_NODES * sizeof(int), stream);

    const int nb_n = (N_NODES + 255) / 256;
    const int nb_w = (N_NODES * 64 + 255) / 256;   // one wave per node

    k_gemm1_hist<<<NB_G + NB_H, 256, 0, stream>>>(x, W1, as1, ad1, ei,
                                                  h1b, s1, d1, cnt, rank);
    k_scan_a<<<NCH, 256, 0, stream>>>(cnt, row_ptr, bsum);
    k_scan_c2<<<(N_NODES + 256) / 256, 256, 0, stream>>>(row_ptr, bsum, srcs);
    k_scatter<<<SLICES * NCHUNK, 256, 0, stream>>>(ei, row_ptr, rank, srcs);
    k_agg1<<<nb_w, 256, 0, stream>>>(row_ptr, srcs, h1b, s1, d1, b1, x2b);
    k_node1<<<nb_n, 256, 0, stream>>>(x2b, W2, as2, ad2, h2b, s2, d2);
    k_agg2<<<nb_w, 256, 0, stream>>>(row_ptr, srcs, h2b, s2, d2, b2, out);
}